// Round 1
// baseline (505.220 us; speedup 1.0000x reference)
//
#include <hip/hip_runtime.h>

// HashGrid2D: out[i, :] = table[hash(positions[i]), :]
// hash = ((floor(x)*73856093) ^ (floor(y)*19349663)) & (2^19 - 1)
// uint32 wrapping mul is exact for the low 19 bits; operands non-negative.
//
// R3 -> R4: 332us = 6 G random-128B-accesses/s, the DRAM random-access wall
// (stream roofline is ~52us; fillBuffer measures 6.5 TB/s). The 64MB table
// can't stay cached: per-XCD L2 is 4MB (6% hit) and the 256MB write stream
// (+1GB harness memsets) cycles L3. nt hints only bought 3% (341->332).
// Fix: SLICE the hash space into 16 x 4MB table slices, grid.y = slice.
// x-major dispatch runs slice passes roughly back-to-back, so the active
// table window is 4MB -> L2/L3 resident by touch frequency. Each pass
// rescans positions (16MB, L3-resident after pass 0) and handles only
// rows whose hash is in-slice; every row is written exactly once.
// Mapping: thread-per-row x 4 rows/thread (fewer waves, full-width hash
// check); 8x16B row gather/stores merge to full lines in L2. Plain cached
// loads/stores everywhere - we WANT pos/table cached now.

#define HASH_MASK ((1u << 19) - 1u)
#define NSLICE 16
#define SLICE_SHIFT 15   // 19-bit hash, 16 slices -> top 4 bits select slice
#define RPT 4            // rows per thread

typedef float vfloat2 __attribute__((ext_vector_type(2)));
typedef float vfloat4 __attribute__((ext_vector_type(4)));

__global__ __launch_bounds__(256) void HashGrid2D_37383395344981_kernel(
    const vfloat2* __restrict__ pos,
    const vfloat4* __restrict__ table,   // HASH_SIZE x 8 vfloat4 (=32 floats)
    vfloat4* __restrict__ out,           // N x 8 vfloat4
    int n)
{
    const unsigned slice = blockIdx.y;
    const int base = blockIdx.x * (256 * RPT) + threadIdx.x;

    // Issue all position loads up front (MLP); L3-hit after pass 0.
    vfloat2 p[RPT];
#pragma unroll
    for (int j = 0; j < RPT; ++j) {
        int r = base + j * 256;
        if (r < n) p[j] = pos[r];
    }

#pragma unroll
    for (int j = 0; j < RPT; ++j) {
        int r = base + j * 256;
        if (r >= n) continue;
        unsigned ix = (unsigned)(int)floorf(p[j].x);
        unsigned iy = (unsigned)(int)floorf(p[j].y);
        unsigned h = ((ix * 73856093u) ^ (iy * 19349663u)) & HASH_MASK;
        if ((h >> SLICE_SHIFT) != slice) continue;   // not this pass's slice

        // Gather one 128B table row (hot 4MB slice -> L2/L3 hit) and
        // write it out; the 8x16B stores merge to full lines in L2.
        const vfloat4* __restrict__ trow = table + (size_t)h * 8;
        vfloat4* __restrict__ orow = out + (size_t)r * 8;
        vfloat4 v0 = trow[0]; vfloat4 v1 = trow[1];
        vfloat4 v2 = trow[2]; vfloat4 v3 = trow[3];
        vfloat4 v4 = trow[4]; vfloat4 v5 = trow[5];
        vfloat4 v6 = trow[6]; vfloat4 v7 = trow[7];
        orow[0] = v0; orow[1] = v1; orow[2] = v2; orow[3] = v3;
        orow[4] = v4; orow[5] = v5; orow[6] = v6; orow[7] = v7;
    }
}

extern "C" void kernel_launch(void* const* d_in, const int* in_sizes, int n_in,
                              void* d_out, int out_size, void* d_ws, size_t ws_size,
                              hipStream_t stream) {
    const vfloat2* pos   = (const vfloat2*)d_in[0];
    const vfloat4* table = (const vfloat4*)d_in[1];
    vfloat4* out = (vfloat4*)d_out;

    int n = in_sizes[0] / 2;            // N positions (each has x,y)
    int rows_per_block = 256 * RPT;
    dim3 grid((unsigned)((n + rows_per_block - 1) / rows_per_block), NSLICE);

    HashGrid2D_37383395344981_kernel<<<grid, dim3(256), 0, stream>>>(pos, table, out, n);
}

// Round 2
// 358.109 us; speedup vs baseline: 1.4108x; 1.4108x over previous
//
#include <hip/hip_runtime.h>

// HashGrid2D: out[i, :] = table[hash(positions[i]), :]
// hash = ((floor(x)*73856093) ^ (floor(y)*19349663)) & (2^19 - 1)
//
// R4 post-mortem: slice-by-rescan fixed locality (FETCH 227MB) but the
// 1/16-sparse lane mask made every gather/store request ~half-empty ->
// 1.78 TB/s, 274us kernel (505us graded). Divergence, not locality, was
// the new wall.
// R5: two-phase compaction through d_ws.
//   P1: bucketize rows by hash-slice (16 slices x 4MB of table each).
//       Block-local LDS-atomic ranks + 1 global atomicAdd/slice/block;
//       scatter (hash,row) u64 into per-slice buckets. Dense, no gathers.
//   P2: per slice, dense waves: 8 lanes/row, 4 rows/thread. Table gathers
//       confined to a 4MB window -> L2-resident; 128B coalesced loads and
//       nt stores. Flat grid, XCD-affine slice = (b&7)+8*half so each
//       XCD's 4MB L2 holds exactly one slice -> table HBM-fetched ~once.
// Bucket overflow (>>40 sigma) falls back to direct gather in P1;
// ws too small falls back to the R3 single-kernel path.

#define HASH_MASK ((1u << 19) - 1u)
#define NSLICE 16
#define SLICE_SHIFT 15
#define P1_RPT 8
#define P1_BLOCK 256
#define P2_ROWS_PER_BLOCK 128   // 256 threads / 8 lanes-per-row * 4 rows/thread

typedef float vfloat2 __attribute__((ext_vector_type(2)));
typedef float vfloat4 __attribute__((ext_vector_type(4)));

__global__ void hg_init(unsigned* gcount) {
    if (threadIdx.x < NSLICE) gcount[threadIdx.x] = 0u;
}

__global__ __launch_bounds__(P1_BLOCK) void hg_phase1(
    const vfloat2* __restrict__ pos,
    const vfloat4* __restrict__ table,
    vfloat4* __restrict__ out,
    unsigned* __restrict__ gcount,
    unsigned long long* __restrict__ bucket,   // NSLICE x cap
    int n, unsigned cap)
{
    __shared__ unsigned lbin[NSLICE];
    __shared__ unsigned gbase[NSLICE];
    if (threadIdx.x < NSLICE) lbin[threadIdx.x] = 0u;
    __syncthreads();

    const int base = blockIdx.x * (P1_BLOCK * P1_RPT) + threadIdx.x;

    vfloat2 p[P1_RPT];
#pragma unroll
    for (int j = 0; j < P1_RPT; ++j) {
        int r = base + j * P1_BLOCK;
        if (r < n) p[j] = __builtin_nontemporal_load(&pos[r]);
    }

    unsigned h[P1_RPT], rank[P1_RPT];
#pragma unroll
    for (int j = 0; j < P1_RPT; ++j) {
        int r = base + j * P1_BLOCK;
        if (r < n) {
            unsigned ix = (unsigned)(int)floorf(p[j].x);
            unsigned iy = (unsigned)(int)floorf(p[j].y);
            h[j] = ((ix * 73856093u) ^ (iy * 19349663u)) & HASH_MASK;
            rank[j] = atomicAdd(&lbin[h[j] >> SLICE_SHIFT], 1u);
        }
    }
    __syncthreads();

    if (threadIdx.x < NSLICE)
        gbase[threadIdx.x] = atomicAdd(&gcount[threadIdx.x], lbin[threadIdx.x]);
    __syncthreads();

#pragma unroll
    for (int j = 0; j < P1_RPT; ++j) {
        int r = base + j * P1_BLOCK;
        if (r >= n) continue;
        unsigned s = h[j] >> SLICE_SHIFT;
        unsigned idx = gbase[s] + rank[j];
        if (idx < cap) {
            unsigned long long e = ((unsigned long long)h[j] << 32) | (unsigned)r;
            __builtin_nontemporal_store(e, &bucket[(size_t)s * cap + idx]);
        } else {
            // statistically ~impossible bucket overflow: direct gather keeps
            // correctness unconditional.
            const vfloat4* trow = table + (size_t)h[j] * 8;
            vfloat4* orow = out + (size_t)r * 8;
#pragma unroll
            for (int c = 0; c < 8; ++c) orow[c] = trow[c];
        }
    }
}

__global__ __launch_bounds__(256) void hg_phase2(
    const vfloat4* __restrict__ table,
    vfloat4* __restrict__ out,
    const unsigned* __restrict__ gcount,
    const unsigned long long* __restrict__ bucket,
    unsigned cap, unsigned gx_half)
{
    // XCD-affine: dispatch round-robins blocks over 8 XCDs (b%8), so slice
    // (b&7)+8*half keeps one 4MB slice per XCD-L2, two sequential passes.
    unsigned b = blockIdx.x;
    unsigned half = (b >= gx_half) ? 1u : 0u;
    unsigned bb = b - half * gx_half;          // gx_half % 8 == 0
    unsigned slice = (bb & 7u) + 8u * half;
    unsigned ib = bb >> 3;                      // block index within slice

    unsigned cnt = gcount[slice];
    if (cnt > cap) cnt = cap;

    const unsigned long long* sb = bucket + (size_t)slice * cap;
    unsigned i0 = ib * P2_ROWS_PER_BLOCK + (threadIdx.x >> 3);
    int c = threadIdx.x & 7;

#pragma unroll
    for (int j = 0; j < 4; ++j) {
        unsigned i = i0 + j * 32;
        if (i >= cnt) continue;
        unsigned long long e = __builtin_nontemporal_load(&sb[i]);
        unsigned h = (unsigned)(e >> 32);
        unsigned r = (unsigned)e;
        vfloat4 v = table[(size_t)h * 8 + c];                 // L2-hot 4MB window
        __builtin_nontemporal_store(v, &out[(size_t)r * 8 + c]);
    }
}

// R3-style fallback if the workspace is too small.
__global__ __launch_bounds__(256) void hg_simple(
    const vfloat2* __restrict__ pos,
    const vfloat4* __restrict__ table,
    vfloat4* __restrict__ out,
    int n)
{
    int gid = blockIdx.x * blockDim.x + threadIdx.x;
    int r = gid >> 3;
    int c = gid & 7;
    if (r >= n) return;
    vfloat2 p = __builtin_nontemporal_load(&pos[r]);
    unsigned ix = (unsigned)(int)floorf(p.x);
    unsigned iy = (unsigned)(int)floorf(p.y);
    unsigned h = ((ix * 73856093u) ^ (iy * 19349663u)) & HASH_MASK;
    vfloat4 v = table[(size_t)h * 8 + c];
    __builtin_nontemporal_store(v, &out[(size_t)r * 8 + c]);
}

extern "C" void kernel_launch(void* const* d_in, const int* in_sizes, int n_in,
                              void* d_out, int out_size, void* d_ws, size_t ws_size,
                              hipStream_t stream) {
    const vfloat2* pos   = (const vfloat2*)d_in[0];
    const vfloat4* table = (const vfloat4*)d_in[1];
    vfloat4* out = (vfloat4*)d_out;

    int n = in_sizes[0] / 2;

    unsigned cap = (unsigned)(n / NSLICE + n / (NSLICE * 4) + 4096);
    size_t need = 64 + (size_t)NSLICE * cap * 8ull;

    if (ws_size < need) {
        long long threads = (long long)n * 8;
        int grid = (int)((threads + 255) / 256);
        hg_simple<<<grid, 256, 0, stream>>>(pos, table, out, n);
        return;
    }

    unsigned* gcount = (unsigned*)d_ws;
    unsigned long long* bucket = (unsigned long long*)((char*)d_ws + 64);

    hg_init<<<1, 64, 0, stream>>>(gcount);

    int p1_grid = (n + P1_BLOCK * P1_RPT - 1) / (P1_BLOCK * P1_RPT);
    hg_phase1<<<p1_grid, P1_BLOCK, 0, stream>>>(pos, table, out, gcount, bucket, n, cap);

    unsigned bps = (cap + P2_ROWS_PER_BLOCK - 1) / P2_ROWS_PER_BLOCK; // blocks per slice
    unsigned gx_half = 8u * bps;                                       // slices 0-7, then 8-15
    hg_phase2<<<2 * gx_half, 256, 0, stream>>>(table, out, gcount, bucket, cap, gx_half);
}